// Round 4
// baseline (156.733 us; speedup 1.0000x reference)
//
#include <hip/hip_runtime.h>
#include <hip/hip_bf16.h>
#include <cmath>

#define HH 256
#define WW 256
#define BB 64
#define RR 4                  // 9 taps: dropped weight exp(-12.5)=3.7e-6 -> error ~4e-5
#define OROWS 32              // output rows per block strip
#define NSTRIP (HH / OROWS)   // 8
#define TROWS (OROWS + 2*RR)  // 40 h-blurred rows in LDS
#define TSTR 260              // tmp row stride (dwords): rows rotate 4 banks
#define MAPS_BYTES ((size_t)3 * BB * HH * WW * 2)   // 25,165,824 B of bf16 maps in ws

static __device__ __forceinline__ float bin(float v) { return (v > 0.0f) ? 1.0f : 0.0f; }

static __device__ __forceinline__ unsigned pk_bf16(float a, float b) {
    __hip_bfloat162 h = __float22bfloat162_rn(make_float2(a, b));
    return *reinterpret_cast<unsigned*>(&h);
}
static __device__ __forceinline__ float2 up_bf16(unsigned u) {
    __hip_bfloat162 h = *reinterpret_cast<__hip_bfloat162*>(&u);
    return __bfloat1622float2(h);
}

// ---------------------------------------------------------------------------
// Splat: separable 9-tap Gaussian of binarized mask, one block per
// (b, map, 32-row strip). h-pass straight from global (registers) -> LDS rows
// (full-row-contiguous b128); v-pass 8 rows/wave; packed-bf16 planes -> ws.
// Per-block max (fp32) -> maxws[z*8+strip]. No atomics.
// map 0: splat(x[:,2],s=1)->plane0 ; 1: x[:,1]->plane1 ; 2: x[:,3],s=.5->plane2
// ---------------------------------------------------------------------------
__global__ __launch_bounds__(256) void splat_kernel(const float* __restrict__ x,
                                                    unsigned short* __restrict__ maps,
                                                    float* __restrict__ maxws) {
    __shared__ float tmp[TROWS * TSTR];   // 40*260*4 = 41600 B -> 3 blocks/CU
    __shared__ float wred[4];

    const int strip = blockIdx.x;        // 0..7
    const int z = blockIdx.y;            // 0..191 = b*3+m
    const int b = z / 3;
    const int m = z - 3 * b;
    const int src_c = (m == 0) ? 2 : ((m == 1) ? 1 : 3);
    const float inv2s2 = (m == 2) ? 2.0f : 0.5f;   // 1/(2 sigma^2)

    float w[RR + 1];
#pragma unroll
    for (int d = 0; d <= RR; ++d) w[d] = expf(-(float)(d * d) * inv2s2);

    const int ti0 = strip * OROWS;
    const float* xc = x + (((size_t)b * 4 + src_c) << 16);
    const int tid = threadIdx.x;

    // ---- h-stage: 40 rows x 32 groups (8 outputs each) = 1280 tasks ----
#pragma unroll
    for (int t = 0; t < 5; ++t) {
        int idx = tid + t * 256;
        int r = idx >> 5;                // tmp row 0..39
        int g = idx & 31;                // cols 8g..8g+7
        int gi = ti0 + r - RR;           // image row
        float4 q0 = make_float4(0.f,0.f,0.f,0.f), q1 = q0, q2 = q0, q3 = q0;
        if (gi >= 0 && gi < HH) {
            const float4* row = (const float4*)(xc + ((size_t)gi << 8));
            int i0 = (g > 0) ? (2 * g - 1) : 0;
            int i3 = (g < 31) ? (2 * g + 2) : 63;
            q0 = row[i0];
            q1 = row[2 * g];
            q2 = row[2 * g + 1];
            q3 = row[i3];
            if (g == 0)  q0 = make_float4(0.f,0.f,0.f,0.f);
            if (g == 31) q3 = make_float4(0.f,0.f,0.f,0.f);
        }
        float a[16] = {bin(q0.x), bin(q0.y), bin(q0.z), bin(q0.w),
                       bin(q1.x), bin(q1.y), bin(q1.z), bin(q1.w),
                       bin(q2.x), bin(q2.y), bin(q2.z), bin(q2.w),
                       bin(q3.x), bin(q3.y), bin(q3.z), bin(q3.w)};
        float o[8];
#pragma unroll
        for (int j = 0; j < 8; ++j) {
            o[j] = w[4] * (a[j]     + a[j + 8])
                 + w[3] * (a[j + 1] + a[j + 7])
                 + w[2] * (a[j + 2] + a[j + 6])
                 + w[1] * (a[j + 3] + a[j + 5])
                 + w[0] *  a[j + 4];
        }
        float* trow = &tmp[r * TSTR + 8 * g];
        *(float4*)trow       = make_float4(o[0], o[1], o[2], o[3]);
        *(float4*)(trow + 4) = make_float4(o[4], o[5], o[6], o[7]);
    }
    __syncthreads();

    // ---- v-stage: wave wv -> out rows 8wv..8wv+7, lane c -> cols 4c..4c+3 ----
    const int c = tid & 63;
    const int wv = tid >> 6;             // 0..3
    float4 acc[8];
#pragma unroll
    for (int rr = 0; rr < 8; ++rr) acc[rr] = make_float4(0.f,0.f,0.f,0.f);
#pragma unroll
    for (int k = 0; k < 16; ++k) {       // tmp rows 8wv+k; contiguous b128 reads
        float4 v = *(const float4*)&tmp[(8 * wv + k) * TSTR + 4 * c];
#pragma unroll
        for (int rr = 0; rr < 8; ++rr) {
            int d = k - RR - rr;         // compile-time; dead taps pruned
            if (d >= -RR && d <= RR) {
                float wk = w[d < 0 ? -d : d];
                acc[rr].x += wk * v.x; acc[rr].y += wk * v.y;
                acc[rr].z += wk * v.z; acc[rr].w += wk * v.w;
            }
        }
    }

    unsigned short* mp = maps + ((size_t)z << 16);
    float lmax = 0.0f;
#pragma unroll
    for (int rr = 0; rr < 8; ++rr) {
        int row = ti0 + 8 * wv + rr;
        uint2 pk = make_uint2(pk_bf16(acc[rr].x, acc[rr].y), pk_bf16(acc[rr].z, acc[rr].w));
        *(uint2*)&mp[(row << 8) + 4 * c] = pk;
        lmax = fmaxf(lmax, fmaxf(fmaxf(acc[rr].x, acc[rr].y), fmaxf(acc[rr].z, acc[rr].w)));
    }

#pragma unroll
    for (int off = 32; off > 0; off >>= 1)
        lmax = fmaxf(lmax, __shfl_down(lmax, off, 64));
    if ((tid & 63) == 0) wred[tid >> 6] = lmax;
    __syncthreads();
    if (tid == 0)
        maxws[z * NSTRIP + strip] = fmaxf(fmaxf(wred[0], wred[1]), fmaxf(wred[2], wred[3]));
}

// ---------------------------------------------------------------------------
// Finalize: reduce 24 strip-maxes per batch, read bf16 maps from ws, write all
// 5 fp32 output planes (ch0 copy, t, c, h, t*c). 8 px per thread-iter.
// ---------------------------------------------------------------------------
__global__ __launch_bounds__(256) void finalize_kernel(const float* __restrict__ x,
                                                       float* __restrict__ out,
                                                       const unsigned short* __restrict__ maps,
                                                       const float* __restrict__ maxws) {
    __shared__ float lds[3 * NSTRIP];
    const int b = blockIdx.x >> 3;
    const int slab = blockIdx.x & 7;
    const int tid = threadIdx.x;

    if (tid < 3 * NSTRIP) lds[tid] = maxws[b * 3 * NSTRIP + tid];
    __syncthreads();

    float mt = 0.f, mc = 0.f, mh = 0.f;
#pragma unroll
    for (int s = 0; s < NSTRIP; ++s) {
        mt = fmaxf(mt, lds[s]);
        mc = fmaxf(mc, lds[NSTRIP + s]);
        mh = fmaxf(mh, lds[2 * NSTRIP + s]);
    }
    if (mt == 0.f) mt = 1.f;
    if (mc == 0.f) mc = 1.f;
    if (mh == 0.f) mh = 1.f;
    const float rt = 1.f / mt, rc = 1.f / mc, rh = 1.f / mh;

    const int plane4 = HH * WW / 4;                 // 16384 float4/plane
    const uint4* tp = (const uint4*)(maps + (((size_t)b * 3 + 0) << 16));
    const uint4* cp = (const uint4*)(maps + (((size_t)b * 3 + 1) << 16));
    const uint4* hp = (const uint4*)(maps + (((size_t)b * 3 + 2) << 16));
    const float4* x0 = (const float4*)(x + ((size_t)b * 4 << 16));
    float4* o = (float4*)(out + ((size_t)b * 5 << 16));

#pragma unroll
    for (int i = 0; i < 4; ++i) {
        int q8 = slab * 1024 + i * 256 + tid;       // 8-px unit
        uint4 tu = tp[q8], cu = cp[q8], hu = hp[q8];

        float2 t0 = up_bf16(tu.x), t1 = up_bf16(tu.y), t2 = up_bf16(tu.z), t3 = up_bf16(tu.w);
        float2 c0 = up_bf16(cu.x), c1 = up_bf16(cu.y), c2 = up_bf16(cu.z), c3 = up_bf16(cu.w);
        float2 h0 = up_bf16(hu.x), h1 = up_bf16(hu.y), h2 = up_bf16(hu.z), h3 = up_bf16(hu.w);

        float4 ta = make_float4(t0.x * rt, t0.y * rt, t1.x * rt, t1.y * rt);
        float4 tb = make_float4(t2.x * rt, t2.y * rt, t3.x * rt, t3.y * rt);
        float4 ca = make_float4(c0.x * rc, c0.y * rc, c1.x * rc, c1.y * rc);
        float4 cb = make_float4(c2.x * rc, c2.y * rc, c3.x * rc, c3.y * rc);
        float4 ha = make_float4(h0.x * rh, h0.y * rh, h1.x * rh, h1.y * rh);
        float4 hb = make_float4(h2.x * rh, h2.y * rh, h3.x * rh, h3.y * rh);
        float4 ma = make_float4(ta.x * ca.x, ta.y * ca.y, ta.z * ca.z, ta.w * ca.w);
        float4 mb = make_float4(tb.x * cb.x, tb.y * cb.y, tb.z * cb.z, tb.w * cb.w);

        int q = 2 * q8;
        o[q]     = x0[q];
        o[q + 1] = x0[q + 1];
        o[plane4 + q]     = ta;  o[plane4 + q + 1]     = tb;
        o[2 * plane4 + q] = ca;  o[2 * plane4 + q + 1] = cb;
        o[3 * plane4 + q] = ha;  o[3 * plane4 + q + 1] = hb;
        o[4 * plane4 + q] = ma;  o[4 * plane4 + q + 1] = mb;
    }
}

extern "C" void kernel_launch(void* const* d_in, const int* in_sizes, int n_in,
                              void* d_out, int out_size, void* d_ws, size_t ws_size,
                              hipStream_t stream) {
    const float* x = (const float*)d_in[0];
    float* out = (float*)d_out;
    char* wsb = (char*)d_ws;
    unsigned short* maps = (unsigned short*)wsb;            // 3*64 bf16 planes
    float* maxws = (float*)(wsb + MAPS_BYTES);              // 192*8 fp32 maxes

    dim3 g1(NSTRIP, BB * 3);   // 8 strips x 192 (b,map) = 1536 blocks
    hipLaunchKernelGGL(splat_kernel, g1, dim3(256), 0, stream, x, maps, maxws);

    hipLaunchKernelGGL(finalize_kernel, dim3(BB * 8), dim3(256), 0, stream,
                       x, out, maps, maxws);
}